// Round 3
// baseline (874.911 us; speedup 1.0000x reference)
//
#include <hip/hip_runtime.h>
#include <hip/hip_bf16.h>

#define DIM 32

// ---------------- bf16 <-> fp32 helpers (bit-level) ------------------------
__device__ __forceinline__ float b2f(ushort h) {
    union { float f; unsigned u; } u; u.u = ((unsigned)h) << 16; return u.f;
}
__device__ __forceinline__ ushort f2b(float f) {
    union { __hip_bfloat16 b; ushort u; } c; c.b = __float2bfloat16(f); return c.u;
}

// ---------------------------------------------------------------------------
// Probe: flags[0] = idx layout (0 = int32, 1 = int64 low-words).
//        flags[1] = float-input dtype (1 = bf16, 0 = fp32).
// Round-1/2 evidence says inputs are fp32 and idx behavior TBD; probe keeps
// us correct under either, costs ~2 us once.
// ---------------------------------------------------------------------------
__global__ void probe_kernel(const ushort* __restrict__ xh,
                             const int* __restrict__ idx,
                             int* __restrict__ flags) {
    if (threadIdx.x == 0 && blockIdx.x == 0) {
        int cnt = 0;
        for (int i = 0; i < 128; ++i) {
            int e = (xh[2 * i] >> 7) & 0xFF;   // exponent field of even halves
            if (e >= 100 && e <= 135) ++cnt;   // bf16 N(0,1): ~all in range
        }
        flags[1] = (cnt >= 100) ? 1 : 0;
        int odd_nonzero = 0;
        for (int i = 1; i < 256; i += 2) odd_nonzero += (idx[i] != 0) ? 1 : 0;
        flags[0] = (odd_nonzero == 0) ? 1 : 0; // int64 lowwords: odd words all 0
    }
}

__device__ __forceinline__ int load_idx(const int* __restrict__ idx, size_t pos,
                                        int mode, int n) {
    int v = mode ? idx[2 * pos] : idx[pos];
    return v < 0 ? 0 : (v >= n ? n - 1 : v);
}

__device__ __forceinline__ float load_f(const void* p, size_t i, int bf) {
    return bf ? b2f(((const ushort*)p)[i]) : ((const float*)p)[i];
}

// ---------------------------------------------------------------------------
// K1: Q|K|V = x @ {Wq,Wk,Wv}, fp32 accumulate, stored bf16 (gather bandwidth).
// 256 threads = 8 rows x 32 cols. Weights staged in LDS.
// ---------------------------------------------------------------------------
__global__ void __launch_bounds__(256)
qkv_kernel(const void* __restrict__ x_, const void* __restrict__ Wq_,
           const void* __restrict__ Wk_, const void* __restrict__ Wv_,
           int N, ushort* __restrict__ Q, ushort* __restrict__ K,
           ushort* __restrict__ V, const int* __restrict__ flags) {
    const int bf = flags[1];
    __shared__ float sW[3][DIM * DIM];
    __shared__ float sx[8][DIM];

    const int tid = threadIdx.x;
    for (int i = tid; i < DIM * DIM; i += 256) {
        sW[0][i] = load_f(Wq_, i, bf);
        sW[1][i] = load_f(Wk_, i, bf);
        sW[2][i] = load_f(Wv_, i, bf);
    }

    const int lr  = tid >> 5;
    const int d   = tid & 31;
    const int row = blockIdx.x * 8 + lr;
    if (row < N) sx[lr][d] = load_f(x_, (size_t)row * DIM + d, bf);
    __syncthreads();
    if (row >= N) return;

    float aq = 0.f, ak = 0.f, av = 0.f;
#pragma unroll
    for (int k = 0; k < DIM; ++k) {
        const float xk = sx[lr][k];
        aq += xk * sW[0][k * DIM + d];
        ak += xk * sW[1][k * DIM + d];
        av += xk * sW[2][k * DIM + d];
    }
    const size_t o = (size_t)row * DIM + d;
    Q[o] = f2b(aq); K[o] = f2b(ak); V[o] = f2b(av);
}

// ---------------------------------------------------------------------------
// K2 (fused edge pass): a = exp(clamp((Q[r]·K[s])*scale));
//   acc[r] += a * V[s]   (4 fp32 atomics per lane, 8 lanes per edge)
//   Z[r]   += a          (lane 0)
// Normalize in the epilogue: (Σ a·V)/(Σ a + 1e-6) == reference up to the
// epsilon shift (<=1e-6 rel: Σ exp(s - smax) >= 1). No max pass needed:
// scores ~ N(0,1), |s| < ~7 over 1.6M edges; clamp ±60 prevents Inf always.
// ---------------------------------------------------------------------------
__global__ void __launch_bounds__(256)
edge_kernel(const ushort* __restrict__ Q, const ushort* __restrict__ K,
            const ushort* __restrict__ V, const int* __restrict__ idx,
            int E, int N, float* __restrict__ acc, float* __restrict__ Z,
            const int* __restrict__ flags) {
    const int mode = flags[0];
    const int t = blockIdx.x * 256 + threadIdx.x;
    const int e = t >> 3;
    const int j = t & 7;
    if (e >= E) return;

    const int s = load_idx(idx, (size_t)e, mode, N);
    const int r = load_idx(idx, (size_t)E + e, mode, N);

    const ushort4 qh = ((const ushort4*)(Q + (size_t)r * DIM))[j];
    const ushort4 kh = ((const ushort4*)(K + (size_t)s * DIM))[j];
    float p = b2f(qh.x) * b2f(kh.x) + b2f(qh.y) * b2f(kh.y) +
              b2f(qh.z) * b2f(kh.z) + b2f(qh.w) * b2f(kh.w);
    p += __shfl_xor(p, 1, 8);
    p += __shfl_xor(p, 2, 8);
    p += __shfl_xor(p, 4, 8);

    float sc = p * 0.17677669529663687f;          // 1/sqrt(32)
    sc = fminf(fmaxf(sc, -60.f), 60.f);
    const float a = __expf(sc);

    const ushort4 vh = ((const ushort4*)(V + (size_t)s * DIM))[j];
    float* dst = acc + (size_t)r * DIM + j * 4;
    atomicAdd(dst + 0, a * b2f(vh.x));
    atomicAdd(dst + 1, a * b2f(vh.y));
    atomicAdd(dst + 2, a * b2f(vh.z));
    atomicAdd(dst + 3, a * b2f(vh.w));
    if (j == 0) atomicAdd(Z + r, a);
}

// ---------------------------------------------------------------------------
// K3: out = fp32( x + (acc/(Z+1e-6)) @ Wo )   — OUTPUT IS FP32 (ref dtype)
// ---------------------------------------------------------------------------
__global__ void __launch_bounds__(256)
out_kernel(const void* __restrict__ x_, const void* __restrict__ Wo_,
           const float* __restrict__ acc, const float* __restrict__ Z,
           int N, float* __restrict__ out, const int* __restrict__ flags) {
    const int bf = flags[1];
    __shared__ float sWo[DIM * DIM];
    __shared__ float sa[8][DIM];

    const int tid = threadIdx.x;
    for (int i = tid; i < DIM * DIM; i += 256) sWo[i] = load_f(Wo_, i, bf);

    const int lr  = tid >> 5;
    const int d   = tid & 31;
    const int row = blockIdx.x * 8 + lr;
    if (row < N) {
        const float inv = 1.f / (Z[row] + 1e-6f);
        sa[lr][d] = acc[(size_t)row * DIM + d] * inv;
    }
    __syncthreads();
    if (row >= N) return;

    float o = 0.f;
#pragma unroll
    for (int k = 0; k < DIM; ++k) o += sa[lr][k] * sWo[k * DIM + d];

    const size_t oi = (size_t)row * DIM + d;
    out[oi] = o + load_f(x_, oi, bf);
}

// ---------------------------------------------------------------------------
extern "C" void kernel_launch(void* const* d_in, const int* in_sizes, int n_in,
                              void* d_out, int out_size, void* d_ws, size_t ws_size,
                              hipStream_t stream) {
    const void* x   = d_in[0];
    const int*  idx = (const int*)d_in[1];
    const void* Wq  = d_in[2];
    const void* Wk  = d_in[3];
    const void* Wv  = d_in[4];
    const void* Wo  = d_in[5];
    float* out = (float*)d_out;            // fp32: reference output dtype

    const int N = in_sizes[0] / DIM;       // 100000
    const int E = in_sizes[1] / 2;         // 1600000
    const size_t N32 = (size_t)N * DIM;

    // Workspace (~32.4 MB): Q|K|V bf16, acc fp32, Z fp32, flags
    ushort* Q   = (ushort*)d_ws;
    ushort* K   = Q + N32;
    ushort* V   = K + N32;
    float* acc  = (float*)(V + N32);
    float* Z    = acc + N32;
    int*  flags = (int*)(Z + N);

    probe_kernel<<<1, 64, 0, stream>>>((const ushort*)x, idx, flags);
    hipMemsetAsync(acc, 0, N32 * sizeof(float), stream);
    hipMemsetAsync(Z, 0, (size_t)N * sizeof(float), stream);

    qkv_kernel<<<(N + 7) / 8, 256, 0, stream>>>(x, Wq, Wk, Wv, N, Q, K, V, flags);

    const int edge_blocks = (E * 8 + 255) / 256;
    edge_kernel<<<edge_blocks, 256, 0, stream>>>(Q, K, V, idx, E, N, acc, Z, flags);

    out_kernel<<<(N + 7) / 8, 256, 0, stream>>>(x, Wo, acc, Z, N, out, flags);
}

// Round 4
// 478.592 us; speedup vs baseline: 1.8281x; 1.8281x over previous
//
#include <hip/hip_runtime.h>
#include <hip/hip_bf16.h>

#define DIM 32

// ---------------- bf16 <-> fp32 helpers (bit-level) ------------------------
__device__ __forceinline__ float b2f(ushort h) {
    union { float f; unsigned u; } u; u.u = ((unsigned)h) << 16; return u.f;
}
__device__ __forceinline__ ushort f2b(float f) {
    union { __hip_bfloat16 b; ushort u; } c; c.b = __float2bfloat16(f); return c.u;
}

// ---------------------------------------------------------------------------
// Probe: flags[0] = idx layout (0 = int32, 1 = int64 low-words).
//        flags[1] = float-input dtype (1 = bf16, 0 = fp32).
// ---------------------------------------------------------------------------
__global__ void probe_kernel(const ushort* __restrict__ xh,
                             const int* __restrict__ idx,
                             int* __restrict__ flags) {
    if (threadIdx.x == 0 && blockIdx.x == 0) {
        int cnt = 0;
        for (int i = 0; i < 128; ++i) {
            int e = (xh[2 * i] >> 7) & 0xFF;
            if (e >= 100 && e <= 135) ++cnt;
        }
        flags[1] = (cnt >= 100) ? 1 : 0;
        int odd_nonzero = 0;
        for (int i = 1; i < 256; i += 2) odd_nonzero += (idx[i] != 0) ? 1 : 0;
        flags[0] = (odd_nonzero == 0) ? 1 : 0;
    }
}

__device__ __forceinline__ int load_idx(const int* __restrict__ idx, size_t pos,
                                        int mode, int n) {
    int v = mode ? idx[2 * pos] : idx[pos];
    return v < 0 ? 0 : (v >= n ? n - 1 : v);
}

__device__ __forceinline__ float load_f(const void* p, size_t i, int bf) {
    return bf ? b2f(((const ushort*)p)[i]) : ((const float*)p)[i];
}

// ---------------------------------------------------------------------------
// K1: Q|K|V = x @ {Wq,Wk,Wv}, fp32 accumulate, stored bf16 (gather bandwidth).
// ---------------------------------------------------------------------------
__global__ void __launch_bounds__(256)
qkv_kernel(const void* __restrict__ x_, const void* __restrict__ Wq_,
           const void* __restrict__ Wk_, const void* __restrict__ Wv_,
           int N, ushort* __restrict__ Q, ushort* __restrict__ K,
           ushort* __restrict__ V, const int* __restrict__ flags) {
    const int bf = flags[1];
    __shared__ float sW[3][DIM * DIM];
    __shared__ float sx[8][DIM];

    const int tid = threadIdx.x;
    for (int i = tid; i < DIM * DIM; i += 256) {
        sW[0][i] = load_f(Wq_, i, bf);
        sW[1][i] = load_f(Wk_, i, bf);
        sW[2][i] = load_f(Wv_, i, bf);
    }

    const int lr  = tid >> 5;
    const int d   = tid & 31;
    const int row = blockIdx.x * 8 + lr;
    if (row < N) sx[lr][d] = load_f(x_, (size_t)row * DIM + d, bf);
    __syncthreads();
    if (row >= N) return;

    float aq = 0.f, ak = 0.f, av = 0.f;
#pragma unroll
    for (int k = 0; k < DIM; ++k) {
        const float xk = sx[lr][k];
        aq += xk * sW[0][k * DIM + d];
        ak += xk * sW[1][k * DIM + d];
        av += xk * sW[2][k * DIM + d];
    }
    const size_t o = (size_t)row * DIM + d;
    Q[o] = f2b(aq); K[o] = f2b(ak); V[o] = f2b(av);
}

// ---------------------------------------------------------------------------
// K2: histogram of receivers (1.6M int atomics on 400KB L2-resident array)
// ---------------------------------------------------------------------------
__global__ void __launch_bounds__(256)
hist_kernel(const int* __restrict__ idx, int E, int N,
            int* __restrict__ count, const int* __restrict__ flags) {
    const int mode = flags[0];
    const int t = blockIdx.x * 256 + threadIdx.x;
    if (t >= E) return;
    const int r = load_idx(idx, (size_t)E + t, mode, N);
    atomicAdd(&count[r], 1);
}

// ---------------------------------------------------------------------------
// K3: exclusive prefix scan of count -> base. Single 1024-thread workgroup,
// looping over chunks: per-wave shfl scan + serial scan of 16 wave sums.
// N = 100k -> ~98 chunks, trivial cost.
// ---------------------------------------------------------------------------
__global__ void __launch_bounds__(1024)
scan_kernel(const int* __restrict__ count, int* __restrict__ base, int N) {
    __shared__ int wsum[16];
    __shared__ int sRun;
    __shared__ int sTot;
    const int tid  = threadIdx.x;
    const int lane = tid & 63;
    const int w    = tid >> 6;
    if (tid == 0) sRun = 0;
    __syncthreads();

    for (int start = 0; start < N; start += 1024) {
        const int ii = start + tid;
        const int v  = (ii < N) ? count[ii] : 0;
        int x = v;
        // inclusive wave scan
#pragma unroll
        for (int off = 1; off < 64; off <<= 1) {
            int t2 = __shfl_up(x, off);
            if (lane >= off) x += t2;
        }
        if (lane == 63) wsum[w] = x;
        __syncthreads();
        const int run = sRun;          // capture before update
        __syncthreads();
        if (tid == 0) {
            int a = 0;
#pragma unroll
            for (int k = 0; k < 16; ++k) { int t2 = wsum[k]; wsum[k] = a; a += t2; }
            sTot = a;
        }
        __syncthreads();
        if (ii < N) base[ii] = run + wsum[w] + (x - v);   // exclusive
        __syncthreads();
        if (tid == 0) sRun = run + sTot;
        __syncthreads();
    }
}

// ---------------------------------------------------------------------------
// K4: scatter sender ids into CSR slots (1.6M int atomics for cursors)
// ---------------------------------------------------------------------------
__global__ void __launch_bounds__(256)
scatter_kernel(const int* __restrict__ idx, int E, int N,
               const int* __restrict__ base, int* __restrict__ cursor,
               int* __restrict__ slots, const int* __restrict__ flags) {
    const int mode = flags[0];
    const int t = blockIdx.x * 256 + threadIdx.x;
    if (t >= E) return;
    const int s = load_idx(idx, (size_t)t, mode, N);
    const int r = load_idx(idx, (size_t)E + t, mode, N);
    const int pos = base[r] + atomicAdd(&cursor[r], 1);
    slots[pos] = s;
}

// ---------------------------------------------------------------------------
// K5: fused gather-aggregate + softmax-normalize + @Wo + residual.
// One wave per receiver. 64 lanes = 8 edges x 8 channel-groups (4 ch each).
// No fp32 atomics anywhere. Normalization after reduction:
//   out = x + ((sum a*V)/(sum a + 1e-6)) @ Wo   == reference (division linear)
// ---------------------------------------------------------------------------
__global__ void __launch_bounds__(256)
agg_kernel(const ushort* __restrict__ Q, const ushort* __restrict__ K,
           const ushort* __restrict__ V, const int* __restrict__ slots,
           const int* __restrict__ base, const int* __restrict__ count,
           const void* __restrict__ x_, const void* __restrict__ Wo_,
           int N, float* __restrict__ out, const int* __restrict__ flags) {
    const int bf = flags[1];
    __shared__ float sWo[DIM * DIM];
    __shared__ float shH[4][DIM];

    const int tid = threadIdx.x;
    for (int i2 = tid; i2 < DIM * DIM; i2 += 256) sWo[i2] = load_f(Wo_, i2, bf);

    const int w    = tid >> 6;     // wave in block
    const int lane = tid & 63;
    const int i    = lane >> 3;    // edge sub-slot 0..7
    const int j    = lane & 7;     // channel group 0..7
    const int r    = blockIdx.x * 4 + w;

    float ax = 0.f, ay = 0.f, azc = 0.f, aw = 0.f;  // h accum (4 channels)
    float zsum = 0.f;
    float q0 = 0.f, q1 = 0.f, q2 = 0.f, q3 = 0.f;
    int deg = 0, b0 = 0;

    if (r < N) {
        deg = count[r];
        b0  = base[r];
        const ushort4 qh = *(const ushort4*)(Q + (size_t)r * DIM + j * 4);
        q0 = b2f(qh.x); q1 = b2f(qh.y); q2 = b2f(qh.z); q3 = b2f(qh.w);
    }

    const int chunks = (deg + 7) >> 3;
    for (int cc = 0; cc < chunks; ++cc) {
        const int c     = cc * 8 + i;
        const bool ok   = (c < deg);
        const int  cs   = ok ? c : (deg - 1);        // clamped, deg>=1 here
        const int  s    = slots[b0 + cs];

        const ushort4 kh = *(const ushort4*)(K + (size_t)s * DIM + j * 4);
        float p = q0 * b2f(kh.x) + q1 * b2f(kh.y) + q2 * b2f(kh.z) + q3 * b2f(kh.w);
        p += __shfl_xor(p, 1);
        p += __shfl_xor(p, 2);
        p += __shfl_xor(p, 4);      // full 32-dim dot, all j-lanes of edge i

        float sc = p * 0.17677669529663687f;         // 1/sqrt(32)
        sc = fminf(fmaxf(sc, -60.f), 60.f);
        const float a = ok ? __expf(sc) : 0.f;

        const ushort4 vh = *(const ushort4*)(V + (size_t)s * DIM + j * 4);
        ax += a * b2f(vh.x); ay += a * b2f(vh.y);
        azc += a * b2f(vh.z); aw += a * b2f(vh.w);
        zsum += a;
    }

    // reduce across the 8 edge sub-slots (xor 8,16,32)
#pragma unroll
    for (int off = 8; off < 64; off <<= 1) {
        ax  += __shfl_xor(ax,  off);
        ay  += __shfl_xor(ay,  off);
        azc += __shfl_xor(azc, off);
        aw  += __shfl_xor(aw,  off);
        zsum += __shfl_xor(zsum, off);
    }
    // zsum was replicated over j before reduction? No: each lane accumulated
    // its own zsum identical across j (p fully reduced), so after xor-8/16/32
    // every lane holds Z = sum over all edges. h channels live per-j.

    if (r < N && i == 0) {
        shH[w][j * 4 + 0] = ax;
        shH[w][j * 4 + 1] = ay;
        shH[w][j * 4 + 2] = azc;
        shH[w][j * 4 + 3] = aw;
    }
    __syncthreads();

    if (r < N && lane < DIM) {
        const float inv = 1.f / (zsum + 1e-6f);
        float o = 0.f;
#pragma unroll
        for (int k = 0; k < DIM; ++k) o += shH[w][k] * sWo[k * DIM + lane];
        const size_t oi = (size_t)r * DIM + lane;
        out[oi] = load_f(x_, oi, bf) + inv * o;
    }
}

// ---------------------------------------------------------------------------
extern "C" void kernel_launch(void* const* d_in, const int* in_sizes, int n_in,
                              void* d_out, int out_size, void* d_ws, size_t ws_size,
                              hipStream_t stream) {
    const void* x   = d_in[0];
    const int*  idx = (const int*)d_in[1];
    const void* Wq  = d_in[2];
    const void* Wk  = d_in[3];
    const void* Wv  = d_in[4];
    const void* Wo  = d_in[5];
    float* out = (float*)d_out;            // fp32: reference output dtype

    const int N = in_sizes[0] / DIM;       // 100000
    const int E = in_sizes[1] / 2;         // 1600000
    const size_t N32 = (size_t)N * DIM;

    // Workspace (~27 MB): Q|K|V bf16, count|cursor|base int, slots int, flags
    ushort* Q     = (ushort*)d_ws;
    ushort* K     = Q + N32;
    ushort* V     = K + N32;
    int*  count   = (int*)(V + N32);
    int*  cursor  = count + N;
    int*  base    = cursor + N;
    int*  slots   = base + N;
    int*  flags   = slots + E;

    probe_kernel<<<1, 64, 0, stream>>>((const ushort*)x, idx, flags);
    hipMemsetAsync(count, 0, 2 * (size_t)N * sizeof(int), stream);  // count+cursor

    qkv_kernel<<<(N + 7) / 8, 256, 0, stream>>>(x, Wq, Wk, Wv, N, Q, K, V, flags);

    const int eb = (E + 255) / 256;
    hist_kernel<<<eb, 256, 0, stream>>>(idx, E, N, count, flags);
    scan_kernel<<<1, 1024, 0, stream>>>(count, base, N);
    scatter_kernel<<<eb, 256, 0, stream>>>(idx, E, N, base, cursor, slots, flags);

    agg_kernel<<<(N + 3) / 4, 256, 0, stream>>>(Q, K, V, slots, base, count,
                                                x, Wo, N, out, flags);
}